// Round 7
// baseline (266.995 us; speedup 1.0000x reference)
//
#include <hip/hip_runtime.h>

// Instant-NGP hash-grid encode, two-phase, XCD-pinned, request-balanced,
// L1-bypass gathers with forced MLP=16.
//
// Model (round 6 post-mortem): per-XCD L2 request throughput (~16 req/cyc) is
// the binding constraint; every level issues N*8 = 2.1M 8B gather requests and
// the hash scatters them so L1 (32KB) is useless at every level. Therefore:
//   - schedule levels {L, L+8} -> XCD L%8 (level = blockIdx&15; the 8704->8192
//     grid round-robins blockIdx%8 across XCDs, 16 = 0 mod 8) = exactly 4.19M
//     requests per XCD (perfect balance), hot set ~4MB+small per XCD L2.
//   - gathers use __hip_atomic_load(relaxed, agent scope) -> compiler emits
//     global_load_dwordx2 ... sc0: served from L2, no L1 allocate/fill, with
//     compiler-managed waitcnt (safe, unlike raw-asm loads).
//   - all 16 results pinned simultaneously live via empty asm (MLP=16/wave).
// Phase 2: float4 LDS transpose ws[16][N] -> out[N][16].

#define HG_N_LEVELS   16
#define HG_TABLE_SIZE 524288u
#define HG_TABLE_MASK (HG_TABLE_SIZE - 1u)

typedef float vf2 __attribute__((ext_vector_type(2)));
typedef float vf4 __attribute__((ext_vector_type(4)));

__device__ __forceinline__ void hg_prep(
    float px, float py, float pz, float res,
    unsigned* __restrict__ idx, float* __restrict__ w)
{
    const float lim = 1.0f - 1e-6f;
    float ux = fminf(fmaxf(px + 0.5f, 0.0f), lim);
    float uy = fminf(fmaxf(py + 0.5f, 0.0f), lim);
    float uz = fminf(fmaxf(pz + 0.5f, 0.0f), lim);
    float fx = ux * res, fy = uy * res, fz = uz * res;
    float x0f = floorf(fx), y0f = floorf(fy), z0f = floorf(fz);
    float wx1 = fx - x0f, wy1 = fy - y0f, wz1 = fz - z0f;
    float wx0 = 1.0f - wx1, wy0 = 1.0f - wy1, wz0 = 1.0f - wz1;
    unsigned x0 = (unsigned)x0f, y0 = (unsigned)y0f, z0 = (unsigned)z0f;
    const unsigned P1 = 2654435761u, P2 = 805459861u;
    unsigned hx0 = x0,      hx1 = x0 + 1u;
    unsigned hy0 = y0 * P1, hy1 = (y0 + 1u) * P1;
    unsigned hz0 = z0 * P2, hz1 = (z0 + 1u) * P2;
    idx[0] = (hx0 ^ hy0 ^ hz0) & HG_TABLE_MASK;  w[0] = wx0 * wy0 * wz0;
    idx[1] = (hx0 ^ hy0 ^ hz1) & HG_TABLE_MASK;  w[1] = wx0 * wy0 * wz1;
    idx[2] = (hx0 ^ hy1 ^ hz0) & HG_TABLE_MASK;  w[2] = wx0 * wy1 * wz0;
    idx[3] = (hx0 ^ hy1 ^ hz1) & HG_TABLE_MASK;  w[3] = wx0 * wy1 * wz1;
    idx[4] = (hx1 ^ hy0 ^ hz0) & HG_TABLE_MASK;  w[4] = wx1 * wy0 * wz0;
    idx[5] = (hx1 ^ hy0 ^ hz1) & HG_TABLE_MASK;  w[5] = wx1 * wy0 * wz1;
    idx[6] = (hx1 ^ hy1 ^ hz0) & HG_TABLE_MASK;  w[6] = wx1 * wy1 * wz0;
    idx[7] = (hx1 ^ hy1 ^ hz1) & HG_TABLE_MASK;  w[7] = wx1 * wy1 * wz1;
}

// Agent-scope relaxed 8B load -> global_load_dwordx2 sc0 (L1 bypass, L2 hit).
__device__ __forceinline__ vf2 hg_load_l2(const float2* p) {
    unsigned long long u = __hip_atomic_load(
        (const unsigned long long*)p, __ATOMIC_RELAXED, __HIP_MEMORY_SCOPE_AGENT);
    return __builtin_bit_cast(vf2, u);
}

// ---------- Phase 1: request-balanced level-pinned gather -> ws [16][N] ----------
__global__ __launch_bounds__(256) void hashgrid_gather_lvl(
    const float* __restrict__ xyz,
    const float* __restrict__ tables,
    const int*   __restrict__ resolutions,
    float*       __restrict__ ws,       // [16][n] float2, as floats
    int n_points)
{
    // blockIdx = chunk*16 + level; 16 % 8 == 0 -> XCD = blockIdx%8 = level%8.
    // XCD x serves exactly levels {x, x+8}: perfect request balance.
    const int level = blockIdx.x & 15;
    const int chunk = blockIdx.x >> 4;

    const float res = (float)resolutions[level];
    const float2* __restrict__ tbl =
        (const float2*)tables + (size_t)level * HG_TABLE_SIZE;
    float* __restrict__ wlev = ws + (size_t)level * n_points * 2;

    const int p0 = (chunk << 9) + ((int)threadIdx.x << 1);   // 2 pts/thread
    if (p0 >= n_points) return;
    const bool has1 = (p0 + 1) < n_points;

    float axp, ayp, azp, bxp, byp, bzp;
    const float* xp = xyz + (size_t)p0 * 3;     // 24B/thread: 8-aligned
    if (has1) {
        vf2 c0 = *(const vf2*)(xp);
        vf2 c1 = *(const vf2*)(xp + 2);
        vf2 c2 = *(const vf2*)(xp + 4);
        axp = c0.x; ayp = c0.y; azp = c1.x;
        bxp = c1.y; byp = c2.x; bzp = c2.y;
    } else {
        axp = xp[0]; ayp = xp[1]; azp = xp[2];
        bxp = axp; byp = ayp; bzp = azp;
    }

    unsigned ia[8], ib[8]; float wa[8], wb[8];
    hg_prep(axp, ayp, azp, res, ia, wa);
    hg_prep(bxp, byp, bzp, res, ib, wb);

    // issue all 16 gathers (sc0 L1-bypass, compiler-managed waitcnt)
    vf2 fa[8], fb[8];
    #pragma unroll
    for (int k = 0; k < 8; ++k) fa[k] = hg_load_l2(tbl + ia[k]);
    #pragma unroll
    for (int k = 0; k < 8; ++k) fb[k] = hg_load_l2(tbl + ib[k]);

    // Pin all 16 results simultaneously live: loads cannot sink below the
    // memory clobber; uses consume asm outputs -> true per-wave MLP of 16.
    asm volatile(""
        : "+v"(fa[0]), "+v"(fa[1]), "+v"(fa[2]), "+v"(fa[3]),
          "+v"(fa[4]), "+v"(fa[5]), "+v"(fa[6]), "+v"(fa[7]),
          "+v"(fb[0]), "+v"(fb[1]), "+v"(fb[2]), "+v"(fb[3]),
          "+v"(fb[4]), "+v"(fb[5]), "+v"(fb[6]), "+v"(fb[7])
        :
        : "memory");

    float oax = 0.f, oay = 0.f, obx = 0.f, oby = 0.f;
    #pragma unroll
    for (int k = 0; k < 8; ++k) { oax += wa[k] * fa[k].x; oay += wa[k] * fa[k].y; }
    #pragma unroll
    for (int k = 0; k < 8; ++k) { obx += wb[k] * fb[k].x; oby += wb[k] * fb[k].y; }

    if (has1) {
        vf4 v; v.x = oax; v.y = oay; v.z = obx; v.w = oby;
        __builtin_nontemporal_store(v, (vf4*)(wlev + 2 * (size_t)p0)); // 16B aligned
    } else {
        vf2 v; v.x = oax; v.y = oay;
        __builtin_nontemporal_store(v, (vf2*)(wlev + 2 * (size_t)p0));
    }
}

// ---------- Phase 2: transpose ws [16][N] -> out [N][16], float4 both sides ----------
#define TP_PTS 256
#define TP_STRIDE (2 * TP_PTS + 4)   // floats per LDS row (pad 4 -> <=2-way conflicts)

__global__ __launch_bounds__(256) void hashgrid_transpose(
    const float* __restrict__ ws,
    float*       __restrict__ out,
    int n_points)
{
    __shared__ float tile[16 * TP_STRIDE];   // ~33 KB, level-major
    const int p0 = blockIdx.x * TP_PTS;
    const int t  = (int)threadIdx.x;
    const int npts = min(TP_PTS, n_points - p0);

    #pragma unroll
    for (int it = 0; it < 8; ++it) {
        int r  = it * 2 + (t >> 7);
        int q  = t & 127;
        int pt = q * 2;
        if (pt < npts) {
            const float* src = ws + (size_t)r * n_points * 2 + (size_t)(p0 + pt) * 2;
            vf4 v;
            if (pt + 1 < npts) v = *(const vf4*)src;
            else { vf2 v2 = *(const vf2*)src; v.x = v2.x; v.y = v2.y; v.z = 0.f; v.w = 0.f; }
            *(vf4*)&tile[r * TP_STRIDE + 4 * q] = v;
        }
    }
    __syncthreads();

    #pragma unroll
    for (int it = 0; it < 8; ++it) {
        int linear = it * 256 + t;
        int pt = linear >> 3;
        int v4 = linear & 7;
        if (pt < npts) {
            vf4 v;
            #pragma unroll
            for (int k = 0; k < 4; ++k) {
                int e = 4 * v4 + k;
                int lev = e >> 1, f = e & 1;
                v[k] = tile[lev * TP_STRIDE + 2 * pt + f];
            }
            __builtin_nontemporal_store(
                v, (vf4*)(out + (size_t)(p0 + pt) * 32 + 4 * v4));
        }
    }
}

// ---------- Fallback: single-kernel version ----------
__global__ __launch_bounds__(256) void hashgrid_fwd(
    const float* __restrict__ xyz,
    const float* __restrict__ tables,
    const int*   __restrict__ resolutions,
    float*       __restrict__ out,
    int n_points)
{
    int tid   = blockIdx.x * blockDim.x + threadIdx.x;
    int point = tid >> 4;
    int level = tid & 15;
    if (point >= n_points) return;

    float px = xyz[point * 3 + 0];
    float py = xyz[point * 3 + 1];
    float pz = xyz[point * 3 + 2];
    float res = (float)resolutions[level];
    const float2* __restrict__ tbl =
        (const float2*)tables + (size_t)level * HG_TABLE_SIZE;

    unsigned idx[8]; float w[8];
    hg_prep(px, py, pz, res, idx, w);
    vf2 f[8];
    #pragma unroll
    for (int k = 0; k < 8; ++k) f[k] = *(const vf2*)(tbl + idx[k]);
    float ox = 0.f, oy = 0.f;
    #pragma unroll
    for (int k = 0; k < 8; ++k) { ox += w[k] * f[k].x; oy += w[k] * f[k].y; }
    vf2 v; v.x = ox; v.y = oy;
    *(vf2*)(out + (size_t)point * 32 + 2 * level) = v;
}

extern "C" void kernel_launch(void* const* d_in, const int* in_sizes, int n_in,
                              void* d_out, int out_size, void* d_ws, size_t ws_size,
                              hipStream_t stream) {
    const float* xyz         = (const float*)d_in[0];
    const float* tables      = (const float*)d_in[1];
    const int*   resolutions = (const int*)d_in[2];
    float*       out         = (float*)d_out;

    int n_points = in_sizes[0] / 3;
    size_t ws_needed = (size_t)n_points * HG_N_LEVELS * sizeof(float2);

    if (ws_size >= ws_needed) {
        float* ws = (float*)d_ws;
        int C = (n_points + 511) >> 9;          // 512-point chunks per level
        hashgrid_gather_lvl<<<16 * C, 256, 0, stream>>>(
            xyz, tables, resolutions, ws, n_points);
        int tblocks = (n_points + TP_PTS - 1) / TP_PTS;
        hashgrid_transpose<<<tblocks, 256, 0, stream>>>(ws, out, n_points);
    } else {
        int n_threads = n_points * HG_N_LEVELS;
        hashgrid_fwd<<<(n_threads + 255) / 256, 256, 0, stream>>>(
            xyz, tables, resolutions, out, n_points);
    }
}

// Round 8
// 260.346 us; speedup vs baseline: 1.0255x; 1.0255x over previous
//
#include <hip/hip_runtime.h>

// Instant-NGP hash-grid encode, two-phase, XCD-pinned, request-balanced.
//
// Model: per-XCD L2 request throughput is the binding constraint. Every level
// issues N*8 = 2.1M 8B gather requests (hash scatter defeats the 32KB L1 at
// every level), so schedule levels {L, L+8} -> XCD L%8 via level = blockIdx&15
// (grid is a multiple of 16, XCD = blockIdx%8): exactly 4.19M requests/XCD,
// hot set ~4MB+small per XCD L2. Floor ~109us at 16 req/cyc/XCD.
//
// Load path = round 6's proven one: PLAIN cached loads (round 7 showed
// agent-scope/sc0 loads bypass the non-coherent per-XCD L2 entirely ->
// FETCH doubled, 25% regression) + empty-asm pin of all 16 results
// (forces MLP=16/wave; without it the compiler sinks loads, VGPR=20, MLP~4).
// Phase 2: float4 LDS transpose ws[16][N] -> out[N][16].

#define HG_N_LEVELS   16
#define HG_TABLE_SIZE 524288u
#define HG_TABLE_MASK (HG_TABLE_SIZE - 1u)

typedef float vf2 __attribute__((ext_vector_type(2)));
typedef float vf4 __attribute__((ext_vector_type(4)));

__device__ __forceinline__ void hg_prep(
    float px, float py, float pz, float res,
    unsigned* __restrict__ idx, float* __restrict__ w)
{
    const float lim = 1.0f - 1e-6f;
    float ux = fminf(fmaxf(px + 0.5f, 0.0f), lim);
    float uy = fminf(fmaxf(py + 0.5f, 0.0f), lim);
    float uz = fminf(fmaxf(pz + 0.5f, 0.0f), lim);
    float fx = ux * res, fy = uy * res, fz = uz * res;
    float x0f = floorf(fx), y0f = floorf(fy), z0f = floorf(fz);
    float wx1 = fx - x0f, wy1 = fy - y0f, wz1 = fz - z0f;
    float wx0 = 1.0f - wx1, wy0 = 1.0f - wy1, wz0 = 1.0f - wz1;
    unsigned x0 = (unsigned)x0f, y0 = (unsigned)y0f, z0 = (unsigned)z0f;
    const unsigned P1 = 2654435761u, P2 = 805459861u;
    unsigned hx0 = x0,      hx1 = x0 + 1u;
    unsigned hy0 = y0 * P1, hy1 = (y0 + 1u) * P1;
    unsigned hz0 = z0 * P2, hz1 = (z0 + 1u) * P2;
    idx[0] = (hx0 ^ hy0 ^ hz0) & HG_TABLE_MASK;  w[0] = wx0 * wy0 * wz0;
    idx[1] = (hx0 ^ hy0 ^ hz1) & HG_TABLE_MASK;  w[1] = wx0 * wy0 * wz1;
    idx[2] = (hx0 ^ hy1 ^ hz0) & HG_TABLE_MASK;  w[2] = wx0 * wy1 * wz0;
    idx[3] = (hx0 ^ hy1 ^ hz1) & HG_TABLE_MASK;  w[3] = wx0 * wy1 * wz1;
    idx[4] = (hx1 ^ hy0 ^ hz0) & HG_TABLE_MASK;  w[4] = wx1 * wy0 * wz0;
    idx[5] = (hx1 ^ hy0 ^ hz1) & HG_TABLE_MASK;  w[5] = wx1 * wy0 * wz1;
    idx[6] = (hx1 ^ hy1 ^ hz0) & HG_TABLE_MASK;  w[6] = wx1 * wy1 * wz0;
    idx[7] = (hx1 ^ hy1 ^ hz1) & HG_TABLE_MASK;  w[7] = wx1 * wy1 * wz1;
}

// ---------- Phase 1: request-balanced level-pinned gather -> ws [16][N] ----------
__global__ __launch_bounds__(256) void hashgrid_gather_lvl(
    const float* __restrict__ xyz,
    const float* __restrict__ tables,
    const int*   __restrict__ resolutions,
    float*       __restrict__ ws,       // [16][n] float2, as floats
    int n_points)
{
    // blockIdx = chunk*16 + level; XCD = blockIdx%8 = level%8.
    // XCD x serves exactly levels {x, x+8}: perfect request balance.
    const int level = blockIdx.x & 15;
    const int chunk = blockIdx.x >> 4;

    const float res = (float)resolutions[level];
    const float2* __restrict__ tbl =
        (const float2*)tables + (size_t)level * HG_TABLE_SIZE;
    float* __restrict__ wlev = ws + (size_t)level * n_points * 2;

    const int p0 = (chunk << 9) + ((int)threadIdx.x << 1);   // 2 pts/thread
    if (p0 >= n_points) return;
    const bool has1 = (p0 + 1) < n_points;

    float axp, ayp, azp, bxp, byp, bzp;
    const float* xp = xyz + (size_t)p0 * 3;     // 24B/thread: 8-aligned
    if (has1) {
        vf2 c0 = *(const vf2*)(xp);
        vf2 c1 = *(const vf2*)(xp + 2);
        vf2 c2 = *(const vf2*)(xp + 4);
        axp = c0.x; ayp = c0.y; azp = c1.x;
        bxp = c1.y; byp = c2.x; bzp = c2.y;
    } else {
        axp = xp[0]; ayp = xp[1]; azp = xp[2];
        bxp = axp; byp = ayp; bzp = azp;
    }

    unsigned ia[8], ib[8]; float wa[8], wb[8];
    hg_prep(axp, ayp, azp, res, ia, wa);
    hg_prep(bxp, byp, bzp, res, ib, wb);

    // issue all 16 gathers (plain cached loads, compiler-managed waitcnt)
    vf2 fa[8], fb[8];
    #pragma unroll
    for (int k = 0; k < 8; ++k) fa[k] = *(const vf2*)(tbl + ia[k]);
    #pragma unroll
    for (int k = 0; k < 8; ++k) fb[k] = *(const vf2*)(tbl + ib[k]);

    // Pin all 16 results simultaneously live: loads cannot sink below the
    // memory clobber; uses consume asm outputs -> true per-wave MLP of 16.
    asm volatile(""
        : "+v"(fa[0]), "+v"(fa[1]), "+v"(fa[2]), "+v"(fa[3]),
          "+v"(fa[4]), "+v"(fa[5]), "+v"(fa[6]), "+v"(fa[7]),
          "+v"(fb[0]), "+v"(fb[1]), "+v"(fb[2]), "+v"(fb[3]),
          "+v"(fb[4]), "+v"(fb[5]), "+v"(fb[6]), "+v"(fb[7])
        :
        : "memory");

    float oax = 0.f, oay = 0.f, obx = 0.f, oby = 0.f;
    #pragma unroll
    for (int k = 0; k < 8; ++k) { oax += wa[k] * fa[k].x; oay += wa[k] * fa[k].y; }
    #pragma unroll
    for (int k = 0; k < 8; ++k) { obx += wb[k] * fb[k].x; oby += wb[k] * fb[k].y; }

    if (has1) {
        vf4 v; v.x = oax; v.y = oay; v.z = obx; v.w = oby;
        __builtin_nontemporal_store(v, (vf4*)(wlev + 2 * (size_t)p0)); // 16B aligned
    } else {
        vf2 v; v.x = oax; v.y = oay;
        __builtin_nontemporal_store(v, (vf2*)(wlev + 2 * (size_t)p0));
    }
}

// ---------- Phase 2: transpose ws [16][N] -> out [N][16], float4 both sides ----------
#define TP_PTS 256
#define TP_STRIDE (2 * TP_PTS + 4)   // floats per LDS row (pad 4 -> <=2-way conflicts)

__global__ __launch_bounds__(256) void hashgrid_transpose(
    const float* __restrict__ ws,
    float*       __restrict__ out,
    int n_points)
{
    __shared__ float tile[16 * TP_STRIDE];   // ~33 KB, level-major
    const int p0 = blockIdx.x * TP_PTS;
    const int t  = (int)threadIdx.x;
    const int npts = min(TP_PTS, n_points - p0);

    #pragma unroll
    for (int it = 0; it < 8; ++it) {
        int r  = it * 2 + (t >> 7);
        int q  = t & 127;
        int pt = q * 2;
        if (pt < npts) {
            const float* src = ws + (size_t)r * n_points * 2 + (size_t)(p0 + pt) * 2;
            vf4 v;
            if (pt + 1 < npts) v = *(const vf4*)src;
            else { vf2 v2 = *(const vf2*)src; v.x = v2.x; v.y = v2.y; v.z = 0.f; v.w = 0.f; }
            *(vf4*)&tile[r * TP_STRIDE + 4 * q] = v;
        }
    }
    __syncthreads();

    #pragma unroll
    for (int it = 0; it < 8; ++it) {
        int linear = it * 256 + t;
        int pt = linear >> 3;
        int v4 = linear & 7;
        if (pt < npts) {
            vf4 v;
            #pragma unroll
            for (int k = 0; k < 4; ++k) {
                int e = 4 * v4 + k;
                int lev = e >> 1, f = e & 1;
                v[k] = tile[lev * TP_STRIDE + 2 * pt + f];
            }
            __builtin_nontemporal_store(
                v, (vf4*)(out + (size_t)(p0 + pt) * 32 + 4 * v4));
        }
    }
}

// ---------- Fallback: single-kernel version ----------
__global__ __launch_bounds__(256) void hashgrid_fwd(
    const float* __restrict__ xyz,
    const float* __restrict__ tables,
    const int*   __restrict__ resolutions,
    float*       __restrict__ out,
    int n_points)
{
    int tid   = blockIdx.x * blockDim.x + threadIdx.x;
    int point = tid >> 4;
    int level = tid & 15;
    if (point >= n_points) return;

    float px = xyz[point * 3 + 0];
    float py = xyz[point * 3 + 1];
    float pz = xyz[point * 3 + 2];
    float res = (float)resolutions[level];
    const float2* __restrict__ tbl =
        (const float2*)tables + (size_t)level * HG_TABLE_SIZE;

    unsigned idx[8]; float w[8];
    hg_prep(px, py, pz, res, idx, w);
    vf2 f[8];
    #pragma unroll
    for (int k = 0; k < 8; ++k) f[k] = *(const vf2*)(tbl + idx[k]);
    float ox = 0.f, oy = 0.f;
    #pragma unroll
    for (int k = 0; k < 8; ++k) { ox += w[k] * f[k].x; oy += w[k] * f[k].y; }
    vf2 v; v.x = ox; v.y = oy;
    *(vf2*)(out + (size_t)point * 32 + 2 * level) = v;
}

extern "C" void kernel_launch(void* const* d_in, const int* in_sizes, int n_in,
                              void* d_out, int out_size, void* d_ws, size_t ws_size,
                              hipStream_t stream) {
    const float* xyz         = (const float*)d_in[0];
    const float* tables      = (const float*)d_in[1];
    const int*   resolutions = (const int*)d_in[2];
    float*       out         = (float*)d_out;

    int n_points = in_sizes[0] / 3;
    size_t ws_needed = (size_t)n_points * HG_N_LEVELS * sizeof(float2);

    if (ws_size >= ws_needed) {
        float* ws = (float*)d_ws;
        int C = (n_points + 511) >> 9;          // 512-point chunks per level
        hashgrid_gather_lvl<<<16 * C, 256, 0, stream>>>(
            xyz, tables, resolutions, ws, n_points);
        int tblocks = (n_points + TP_PTS - 1) / TP_PTS;
        hashgrid_transpose<<<tblocks, 256, 0, stream>>>(ws, out, n_points);
    } else {
        int n_threads = n_points * HG_N_LEVELS;
        hashgrid_fwd<<<(n_threads + 255) / 256, 256, 0, stream>>>(
            xyz, tables, resolutions, out, n_points);
    }
}

// Round 9
// 217.972 us; speedup vs baseline: 1.2249x; 1.1944x over previous
//
#include <hip/hip_runtime.h>

// Instant-NGP hash-grid encode, two-phase, XCD-pinned (temporal-phased
// schedule), x-paired 16B gathers, forced MLP.
//
// Schedule (round 4/6, proven): XCD x = blockIdx%8; each XCD runs level 8+x
// exclusively first (hot set = one 4MB table, fits 4MiB L2), then a slice of
// level 7, then small levels. Round 3/8 showed concurrent {L, L+8} thrashes
// L2 (FETCH 160-174MB vs 77MB).
//
// Request reduction: hash primes are {1,P1,P2}, so corners (x0,..) and
// (x0+1,..) differ in index by x0^(x0+1) = bit0 when x0 even -> both 8B
// entries in one aligned 16B. Per (y,z) corner pair: one unconditional 16B
// load (always yields corner A; also corner B when x0 even) + predicated 8B
// load of corner B for odd-x0 lanes. Avg 6 requests/point vs 8 (-25% of the
// L2-slot budget, measured at 79% of the 16 req/cyc/XCD ceiling).
//
// Round-7 lesson kept: NO agent-scope/sc0 loads (they bypass the per-XCD L2).
// Round-6 lesson kept: pin all gather results live via empty asm (else the
// compiler sinks loads, VGPR=20, MLP~4).

#define HG_N_LEVELS   16
#define HG_TABLE_SIZE 524288u
#define HG_TABLE_MASK (HG_TABLE_SIZE - 1u)

typedef float vf2 __attribute__((ext_vector_type(2)));
typedef float vf4 __attribute__((ext_vector_type(4)));

// Per-point prep: 4 yz-hash partials + weights + x0.
__device__ __forceinline__ void hg_prep2(
    float px, float py, float pz, float res,
    unsigned* __restrict__ s, float* __restrict__ wyz,
    unsigned* __restrict__ x0out, float* __restrict__ wx)
{
    const float lim = 1.0f - 1e-6f;
    float ux = fminf(fmaxf(px + 0.5f, 0.0f), lim);
    float uy = fminf(fmaxf(py + 0.5f, 0.0f), lim);
    float uz = fminf(fmaxf(pz + 0.5f, 0.0f), lim);
    float fx = ux * res, fy = uy * res, fz = uz * res;
    float x0f = floorf(fx), y0f = floorf(fy), z0f = floorf(fz);
    float wx1 = fx - x0f, wy1 = fy - y0f, wz1 = fz - z0f;
    float wx0 = 1.0f - wx1, wy0 = 1.0f - wy1, wz0 = 1.0f - wz1;
    unsigned x0 = (unsigned)x0f, y0 = (unsigned)y0f, z0 = (unsigned)z0f;
    const unsigned P1 = 2654435761u, P2 = 805459861u;
    unsigned hy0 = y0 * P1, hy1 = (y0 + 1u) * P1;
    unsigned hz0 = z0 * P2, hz1 = (z0 + 1u) * P2;
    s[0] = hy0 ^ hz0;  wyz[0] = wy0 * wz0;
    s[1] = hy0 ^ hz1;  wyz[1] = wy0 * wz1;
    s[2] = hy1 ^ hz0;  wyz[2] = wy1 * wz0;
    s[3] = hy1 ^ hz1;  wyz[3] = wy1 * wz1;
    *x0out = x0; wx[0] = wx0; wx[1] = wx1;
}

// Legacy full-prep for fallback/tail paths.
__device__ __forceinline__ void hg_prep(
    float px, float py, float pz, float res,
    unsigned* __restrict__ idx, float* __restrict__ w)
{
    unsigned s[4]; float wyz[4], wx[2]; unsigned x0;
    hg_prep2(px, py, pz, res, s, wyz, &x0, wx);
    #pragma unroll
    for (int j = 0; j < 4; ++j) {
        idx[j]     = (x0 ^ s[j]) & HG_TABLE_MASK;        w[j]     = wx[0] * wyz[j];
        idx[4 + j] = ((x0 + 1u) ^ s[j]) & HG_TABLE_MASK; w[4 + j] = wx[1] * wyz[j];
    }
}

// ---------- Phase 1: temporally-phased level-pinned gather -> ws [16][N] ----------
__global__ __launch_bounds__(256) void hashgrid_gather_lvl(
    const float* __restrict__ xyz,
    const float* __restrict__ tables,
    const int*   __restrict__ resolutions,
    float*       __restrict__ ws,       // [16][n] float2, as floats
    int n_points)
{
    const int x    = blockIdx.x & 7;    // XCD (blockIdx%8 round-robin)
    const int slot = blockIdx.x >> 3;   // position in XCD x's work queue
    const int C    = (n_points + 511) >> 9;  // 512-point chunks per level
    const int C8   = (C + 7) >> 3;

    int level, chunk;
    if (slot < C)            { level = 8 + x; chunk = slot; }
    else if (slot < C + C8)  { int j = slot - C; level = 7; chunk = x + (j << 3); }
    else                     { int j = slot - C - C8;
                               if (x >= 6) { level = 6; chunk = (x - 6) + (j << 1); }
                               else        { level = x; chunk = j; } }
    if (chunk >= C) return;

    const float res = (float)resolutions[level];
    const float2* __restrict__ tbl =
        (const float2*)tables + (size_t)level * HG_TABLE_SIZE;
    float* __restrict__ wlev = ws + (size_t)level * n_points * 2;

    const int p0 = (chunk << 9) + ((int)threadIdx.x << 1);   // 2 pts/thread
    if (p0 >= n_points) return;

    if (p0 + 1 < n_points) {
        const float* xp = xyz + (size_t)p0 * 3;
        vf2 c0 = *(const vf2*)(xp);
        vf2 c1 = *(const vf2*)(xp + 2);
        vf2 c2 = *(const vf2*)(xp + 4);

        unsigned sA[4], sB[4], x0A, x0B;
        float wyzA[4], wyzB[4], wxA[2], wxB[2];
        hg_prep2(c0.x, c0.y, c1.x, res, sA, wyzA, &x0A, wxA);
        hg_prep2(c1.y, c2.x, c2.y, res, sB, wyzB, &x0B, wxB);

        unsigned iA0[4], iA1[4], iB0[4], iB1[4];
        #pragma unroll
        for (int j = 0; j < 4; ++j) {
            iA0[j] = (x0A ^ sA[j]) & HG_TABLE_MASK;
            iA1[j] = ((x0A + 1u) ^ sA[j]) & HG_TABLE_MASK;
            iB0[j] = (x0B ^ sB[j]) & HG_TABLE_MASK;
            iB1[j] = ((x0B + 1u) ^ sB[j]) & HG_TABLE_MASK;
        }
        const bool oddA = (x0A & 1u) != 0u;
        const bool oddB = (x0B & 1u) != 0u;

        // 8 unconditional 16B paired loads (line containing corner x-offset 0;
        // for even x0 the same 16B also holds corner x-offset 1).
        vf4 qA[4], qB[4];
        #pragma unroll
        for (int j = 0; j < 4; ++j) qA[j] = *(const vf4*)(tbl + (iA0[j] & ~1u));
        #pragma unroll
        for (int j = 0; j < 4; ++j) qB[j] = *(const vf4*)(tbl + (iB0[j] & ~1u));

        // predicated 8B loads of the +x corner for odd-x0 lanes only
        vf2 eA[4], eB[4];
        #pragma unroll
        for (int j = 0; j < 4; ++j) { eA[j] = (vf2)(0.f); eB[j] = (vf2)(0.f); }
        if (oddA) {
            #pragma unroll
            for (int j = 0; j < 4; ++j) eA[j] = *(const vf2*)(tbl + iA1[j]);
        }
        if (oddB) {
            #pragma unroll
            for (int j = 0; j < 4; ++j) eB[j] = *(const vf2*)(tbl + iB1[j]);
        }

        // Pin everything simultaneously live -> loads can't sink, MLP stays up.
        asm volatile(""
            : "+v"(qA[0]), "+v"(qA[1]), "+v"(qA[2]), "+v"(qA[3]),
              "+v"(qB[0]), "+v"(qB[1]), "+v"(qB[2]), "+v"(qB[3]),
              "+v"(eA[0]), "+v"(eA[1]), "+v"(eA[2]), "+v"(eA[3]),
              "+v"(eB[0]), "+v"(eB[1]), "+v"(eB[2]), "+v"(eB[3])
            :
            : "memory");

        float oax = 0.f, oay = 0.f, obx = 0.f, oby = 0.f;
        #pragma unroll
        for (int j = 0; j < 4; ++j) {
            bool hi = (iA0[j] & 1u) != 0u;
            vf2 lo; lo.x = qA[j].x; lo.y = qA[j].y;
            vf2 hiv; hiv.x = qA[j].z; hiv.y = qA[j].w;
            vf2 f0 = hi ? hiv : lo;                 // corner x-offset 0
            vf2 f1 = oddA ? eA[j] : (hi ? lo : hiv); // corner x-offset 1
            float w0 = wxA[0] * wyzA[j], w1 = wxA[1] * wyzA[j];
            oax += w0 * f0.x + w1 * f1.x;
            oay += w0 * f0.y + w1 * f1.y;
        }
        #pragma unroll
        for (int j = 0; j < 4; ++j) {
            bool hi = (iB0[j] & 1u) != 0u;
            vf2 lo; lo.x = qB[j].x; lo.y = qB[j].y;
            vf2 hiv; hiv.x = qB[j].z; hiv.y = qB[j].w;
            vf2 f0 = hi ? hiv : lo;
            vf2 f1 = oddB ? eB[j] : (hi ? lo : hiv);
            float w0 = wxB[0] * wyzB[j], w1 = wxB[1] * wyzB[j];
            obx += w0 * f0.x + w1 * f1.x;
            oby += w0 * f0.y + w1 * f1.y;
        }

        vf4 v; v.x = oax; v.y = oay; v.z = obx; v.w = oby;
        __builtin_nontemporal_store(v, (vf4*)(wlev + 2 * (size_t)p0)); // 16B aligned
    } else {
        // tail: single point, unpaired path
        float px = xyz[(size_t)p0 * 3 + 0];
        float py = xyz[(size_t)p0 * 3 + 1];
        float pz = xyz[(size_t)p0 * 3 + 2];
        unsigned idx[8]; float w[8];
        hg_prep(px, py, pz, res, idx, w);
        vf2 f[8];
        #pragma unroll
        for (int k = 0; k < 8; ++k) f[k] = *(const vf2*)(tbl + idx[k]);
        float sx = 0.f, sy = 0.f;
        #pragma unroll
        for (int k = 0; k < 8; ++k) { sx += w[k] * f[k].x; sy += w[k] * f[k].y; }
        vf2 v; v.x = sx; v.y = sy;
        __builtin_nontemporal_store(v, (vf2*)(wlev + 2 * (size_t)p0));
    }
}

// ---------- Phase 2: transpose ws [16][N] -> out [N][16], float4 both sides ----------
#define TP_PTS 256
#define TP_STRIDE (2 * TP_PTS + 4)   // floats per LDS row (pad 4 -> <=2-way conflicts)

__global__ __launch_bounds__(256) void hashgrid_transpose(
    const float* __restrict__ ws,
    float*       __restrict__ out,
    int n_points)
{
    __shared__ float tile[16 * TP_STRIDE];   // ~33 KB, level-major
    const int p0 = blockIdx.x * TP_PTS;
    const int t  = (int)threadIdx.x;
    const int npts = min(TP_PTS, n_points - p0);

    #pragma unroll
    for (int it = 0; it < 8; ++it) {
        int r  = it * 2 + (t >> 7);
        int q  = t & 127;
        int pt = q * 2;
        if (pt < npts) {
            const float* src = ws + (size_t)r * n_points * 2 + (size_t)(p0 + pt) * 2;
            vf4 v;
            if (pt + 1 < npts) v = *(const vf4*)src;
            else { vf2 v2 = *(const vf2*)src; v.x = v2.x; v.y = v2.y; v.z = 0.f; v.w = 0.f; }
            *(vf4*)&tile[r * TP_STRIDE + 4 * q] = v;
        }
    }
    __syncthreads();

    #pragma unroll
    for (int it = 0; it < 8; ++it) {
        int linear = it * 256 + t;
        int pt = linear >> 3;
        int v4 = linear & 7;
        if (pt < npts) {
            vf4 v;
            #pragma unroll
            for (int k = 0; k < 4; ++k) {
                int e = 4 * v4 + k;
                int lev = e >> 1, f = e & 1;
                v[k] = tile[lev * TP_STRIDE + 2 * pt + f];
            }
            __builtin_nontemporal_store(
                v, (vf4*)(out + (size_t)(p0 + pt) * 32 + 4 * v4));
        }
    }
}

// ---------- Fallback: single-kernel version ----------
__global__ __launch_bounds__(256) void hashgrid_fwd(
    const float* __restrict__ xyz,
    const float* __restrict__ tables,
    const int*   __restrict__ resolutions,
    float*       __restrict__ out,
    int n_points)
{
    int tid   = blockIdx.x * blockDim.x + threadIdx.x;
    int point = tid >> 4;
    int level = tid & 15;
    if (point >= n_points) return;

    float px = xyz[point * 3 + 0];
    float py = xyz[point * 3 + 1];
    float pz = xyz[point * 3 + 2];
    float res = (float)resolutions[level];
    const float2* __restrict__ tbl =
        (const float2*)tables + (size_t)level * HG_TABLE_SIZE;

    unsigned idx[8]; float w[8];
    hg_prep(px, py, pz, res, idx, w);
    vf2 f[8];
    #pragma unroll
    for (int k = 0; k < 8; ++k) f[k] = *(const vf2*)(tbl + idx[k]);
    float ox = 0.f, oy = 0.f;
    #pragma unroll
    for (int k = 0; k < 8; ++k) { ox += w[k] * f[k].x; oy += w[k] * f[k].y; }
    vf2 v; v.x = ox; v.y = oy;
    *(vf2*)(out + (size_t)point * 32 + 2 * level) = v;
}

extern "C" void kernel_launch(void* const* d_in, const int* in_sizes, int n_in,
                              void* d_out, int out_size, void* d_ws, size_t ws_size,
                              hipStream_t stream) {
    const float* xyz         = (const float*)d_in[0];
    const float* tables      = (const float*)d_in[1];
    const int*   resolutions = (const int*)d_in[2];
    float*       out         = (float*)d_out;

    int n_points = in_sizes[0] / 3;
    size_t ws_needed = (size_t)n_points * HG_N_LEVELS * sizeof(float2);

    if (ws_size >= ws_needed) {
        float* ws = (float*)d_ws;
        int C  = (n_points + 511) >> 9;
        int C8 = (C + 7) >> 3;
        int slots = 2 * C + C8;          // covers the longest XCD queue
        hashgrid_gather_lvl<<<8 * slots, 256, 0, stream>>>(
            xyz, tables, resolutions, ws, n_points);
        int tblocks = (n_points + TP_PTS - 1) / TP_PTS;
        hashgrid_transpose<<<tblocks, 256, 0, stream>>>(ws, out, n_points);
    } else {
        int n_threads = n_points * HG_N_LEVELS;
        hashgrid_fwd<<<(n_threads + 255) / 256, 256, 0, stream>>>(
            xyz, tables, resolutions, out, n_points);
    }
}